// Round 5
// baseline (132.913 us; speedup 1.0000x reference)
//
#include <hip/hip_runtime.h>
#include <type_traits>

// Soft-DTW (gamma=0.1), normalized, batch 64, len 256, dim 8.
// LINEAR-space DP: carry Wlin = 2^{-R/(gamma*ln2)} as (mantissa, int exponent).
// Recurrence: Wlin[i][j] = 2^{Dw} * (Wlin[i-1][j] + Wlin[i-1][j-1] + Wlin[i][j-1])
// -> zero transcendentals on the chain; only exp2(frac(Dw)) per cell (4/step).
typedef _Float16 h2 __attribute__((ext_vector_type(2)));

static constexpr float K1   = -14.426950408889634074f;   // -1/(gamma*ln2)
static constexpr float M2K1 = 28.853900817779268148f;    // -2*K1
static constexpr float KOUT = -0.069314718055994530942f; // -gamma*ln2 (R = KOUT*w)
static constexpr int   SENT = -(1 << 28);                // exponent sentinel for value 0

// wave_shr:1 via DPP: lane l gets lane l-1's value; lane 0 keeps `fill`. Pure VALU.
__device__ __forceinline__ float dppf(float v, float fill) {
    int r = __builtin_amdgcn_update_dpp(__float_as_int(fill), __float_as_int(v),
                                        0x138 /*wave_shr:1*/, 0xf, 0xf, false);
    return __int_as_float(r);
}
__device__ __forceinline__ int dppi(int v, int fill) {
    return __builtin_amdgcn_update_dpp(fill, v, 0x138, 0xf, 0xf, false);
}

__device__ __forceinline__ unsigned pack2(float a, float b) {
    h2 p; p[0] = (_Float16)a; p[1] = (_Float16)b;
    return __builtin_bit_cast(unsigned, p);
}
__device__ __forceinline__ float hdot(h2 a, h2 b, float c) {
#if __has_builtin(__builtin_amdgcn_fdot2)
    return __builtin_amdgcn_fdot2(a, b, c, false);
#else
    return fmaf((float)a[1], (float)b[1], fmaf((float)a[0], (float)b[0], c));
#endif
}

__device__ __forceinline__ float ldx(float x, int n) {   // x * 2^n  (v_ldexp_f32)
#if __has_builtin(__builtin_amdgcn_ldexpf)
    return __builtin_amdgcn_ldexpf(x, n);
#else
    return ldexpf(x, n);
#endif
}
__device__ __forceinline__ float fxm(float x) {          // v_frexp_mant_f32
#if __has_builtin(__builtin_amdgcn_frexp_mantf)
    return __builtin_amdgcn_frexp_mantf(x);
#else
    int e; return frexpf(x, &e);
#endif
}
__device__ __forceinline__ int fxe(float x) {            // v_frexp_exp_i32_f32
#if __has_builtin(__builtin_amdgcn_frexp_expf)
    return __builtin_amdgcn_frexp_expf(x);
#else
    int e; frexpf(x, &e); return e;
#endif
}

__global__ void __attribute__((amdgpu_waves_per_eu(1, 1))) __launch_bounds__(64, 1)
sdtw_kernel(const float* __restrict__ x, const float* __restrict__ y,
            float* __restrict__ out)
{
    const int batch = blockIdx.x;
    const int pair  = blockIdx.y;   // 0: xy, 1: xx, 2: yy
    const int lane  = threadIdx.x;  // lane owns cols 4*lane..4*lane+3

    const float* A  = (pair == 2 ? y : x) + batch * 2048;  // rows side
    const float* Bp = (pair == 1 ? x : y) + batch * 2048;  // cols side

    __shared__ unsigned xHs[4][256];  // f16x2-packed rows
    __shared__ float    nxs[256];     // |x_i|^2 from CONVERTED values

    #pragma unroll
    for (int rr = 0; rr < 4; ++rr) {
        int r = lane + rr * 64;
        float4 a0 = *reinterpret_cast<const float4*>(A + r * 8);
        float4 a1 = *reinterpret_cast<const float4*>(A + r * 8 + 4);
        unsigned u0 = pack2(a0.x, a0.y), u1 = pack2(a0.z, a0.w);
        unsigned u2 = pack2(a1.x, a1.y), u3 = pack2(a1.z, a1.w);
        xHs[0][r] = u0; xHs[1][r] = u1; xHs[2][r] = u2; xHs[3][r] = u3;
        h2 h0 = __builtin_bit_cast(h2, u0), h1 = __builtin_bit_cast(h2, u1);
        h2 h2v = __builtin_bit_cast(h2, u2), h3 = __builtin_bit_cast(h2, u3);
        nxs[r] = hdot(h3, h3, hdot(h2v, h2v, hdot(h1, h1, hdot(h0, h0, 0.0f))));
    }

    h2 bh[4][4]; float Knb[4];
    #pragma unroll
    for (int cc = 0; cc < 4; ++cc) {
        const float* bp = Bp + (4 * lane + cc) * 8;
        float4 b0 = *reinterpret_cast<const float4*>(bp);
        float4 b1 = *reinterpret_cast<const float4*>(bp + 4);
        bh[cc][0] = __builtin_bit_cast(h2, pack2(b0.x, b0.y));
        bh[cc][1] = __builtin_bit_cast(h2, pack2(b0.z, b0.w));
        bh[cc][2] = __builtin_bit_cast(h2, pack2(b1.x, b1.y));
        bh[cc][3] = __builtin_bit_cast(h2, pack2(b1.z, b1.w));
        float nb = hdot(bh[cc][3], bh[cc][3], hdot(bh[cc][2], bh[cc][2],
                   hdot(bh[cc][1], bh[cc][1], hdot(bh[cc][0], bh[cc][0], 0.0f))));
        Knb[cc] = K1 * nb;
    }

    __syncthreads();

    // prev-row linear values (mant, exp); row -1 = BIG -> linear 0
    float Um[4]; int Ue[4];
    #pragma unroll
    for (int j = 0; j < 4; ++j) { Um[j] = 0.0f; Ue[j] = SENT; }
    float ol_m = 0.0f; int ol_e = SENT;                      // own_last (chain out)
    float lp_m = (lane == 0) ? 1.0f : 0.0f;                  // left_prev: R[-1][-1]=0 -> 1.0
    int   lp_e = (lane == 0) ? 0    : SENT;

    unsigned xc[4], xn[4]; float nxc, nxn;
    xc[0]=xHs[0][0]; xc[1]=xHs[1][0]; xc[2]=xHs[2][0]; xc[3]=xHs[3][0]; nxc=nxs[0];

    auto step = [&](auto phc, int s, unsigned (&XC)[4], float& NXC,
                    unsigned (&XN)[4], float& NXN) {
        constexpr int PH = decltype(phc)::value;  // 0 ramp-up, 1 steady, 2 ramp-down
        int ipf = s + 1 - lane;
        ipf = ipf < 0 ? 0 : (ipf > 255 ? 255 : ipf);
        XN[0]=xHs[0][ipf]; XN[1]=xHs[1][ipf]; XN[2]=xHs[2][ipf]; XN[3]=xHs[3][ipf];
        NXN = nxs[ipf];

        float lin_m  = dppf(ol_m, 0.0f);  int lin_e  = dppi(ol_e, SENT);
        float ulin_m = lp_m;              int ulin_e = lp_e;
        lp_m = lin_m; lp_e = lin_e;

        const int i = s - lane;
        bool act = (PH == 0) ? (i >= 0) : (PH == 2) ? (i < 256) : true;
        if (act) {
            // distances (f16 dot2, off-chain) and B = 2^{Dw} split into (mant, int)
            float knx = K1 * NXC;
            h2 xv0 = __builtin_bit_cast(h2, XC[0]);
            h2 xv1 = __builtin_bit_cast(h2, XC[1]);
            h2 xv2 = __builtin_bit_cast(h2, XC[2]);
            h2 xv3 = __builtin_bit_cast(h2, XC[3]);
            float Bm[4]; int Be[4];
            #pragma unroll
            for (int cc = 0; cc < 4; ++cc) {
                float dot = hdot(xv3, bh[cc][3], hdot(xv2, bh[cc][2],
                            hdot(xv1, bh[cc][1], hdot(xv0, bh[cc][0], 0.0f))));
                float Dw  = fmaf(M2K1, dot, knx + Knb[cc]);   // <= ~0
                float t   = truncf(Dw);
                Bm[cc] = __builtin_amdgcn_exp2f(Dw - t);      // in (0.5, 2)
                Be[cc] = (int)t;
            }
            // pre-align prev-row pair: A = U[cc] + UL[cc]  (off the serial chain)
            float Am[4]; int Ae[4];
            {
                float um1 = ulin_m; int ue1 = ulin_e;
                #pragma unroll
                for (int cc = 0; cc < 4; ++cc) {
                    int pe = (Ue[cc] > ue1) ? Ue[cc] : ue1;
                    Am[cc] = ldx(Um[cc], Ue[cc] - pe) + ldx(um1, ue1 - pe);
                    Ae[cc] = pe;
                    um1 = Um[cc]; ue1 = Ue[cc];
                }
            }
            // serial chain: per cell max -> sub -> ldexp -> add -> mul (no trans!)
            float Lm = lin_m; int Le = lin_e;
            float nUm[4]; int nUe[4];
            #pragma unroll
            for (int cc = 0; cc < 4; ++cc) {
                int   em = (Ae[cc] > Le) ? Ae[cc] : Le;
                float S  = ldx(Am[cc], Ae[cc] - em) + ldx(Lm, Le - em);
                float Wm = Bm[cc] * S;
                int   We = Be[cc] + em;
                nUm[cc] = fxm(Wm);                 // renorm (off-chain consumers)
                nUe[cc] = We + fxe(Wm);
                Lm = Wm; Le = We;                  // unnormalized pass-through
            }
            #pragma unroll
            for (int cc = 0; cc < 4; ++cc) { Um[cc] = nUm[cc]; Ue[cc] = nUe[cc]; }
            ol_m = nUm[3]; ol_e = nUe[3];          // normalized handoff
        }
    };

    std::integral_constant<int,0> P0; std::integral_constant<int,1> P1;
    std::integral_constant<int,2> P2;
    for (int s = 0;   s < 64;  s += 2) { step(P0, s, xc, nxc, xn, nxn); step(P0, s+1, xn, nxn, xc, nxc); }
    for (int s = 64;  s < 256; s += 2) { step(P1, s, xc, nxc, xn, nxn); step(P1, s+1, xn, nxn, xc, nxc); }
    for (int s = 256; s < 320; s += 2) { step(P2, s, xc, nxc, xn, nxn); step(P2, s+1, xn, nxn, xc, nxc); }

    if (lane == 63) {
        float w   = (float)ol_e + __builtin_amdgcn_logf(ol_m);  // back to log2 space
        float wgt = (pair == 0) ? (1.0f / 64.0f) : (-0.5f / 64.0f);
        atomicAdd(out, KOUT * w * wgt);
    }
}

extern "C" void kernel_launch(void* const* d_in, const int* in_sizes, int n_in,
                              void* d_out, int out_size, void* d_ws, size_t ws_size,
                              hipStream_t stream)
{
    const float* x = (const float*)d_in[0];
    const float* y = (const float*)d_in[1];
    float* out = (float*)d_out;

    hipMemsetAsync(out, 0, out_size * sizeof(float), stream);
    hipLaunchKernelGGL(sdtw_kernel, dim3(64, 3), dim3(64), 0, stream, x, y, out);
}